// Round 2
// baseline (2994.573 us; speedup 1.0000x reference)
//
#include <hip/hip_runtime.h>
#include <hip/hip_bf16.h>

#define NLAYERS  32
#define NFORC    720
#define NSUB     60
#define DT_STEP  60.0f

// One wave (64 lanes). Lane l (0..31) owns layer l's (U,V). Lanes 32..63
// mirror layer (l&31) but never store. 43,200 sequential Euler steps;
// neighbor coupling via __shfl. State lives entirely in registers.
//
// I/O dtype is sniffed at runtime from pk (~N(-10,0.5)): if staged bf16,
// all 64 bf16 reads land in (-30,-1); if staged f32, the even-index bf16
// reads see f32 low mantissa halves (random sign/exponent) and fail the
// range check almost surely. Output dtype follows the same sniff.
__global__ __launch_bounds__(64, 1)
void junsteak_sim(const void* pk_raw, const void* tax_raw, const void* tay_raw,
                  const void* fc_raw, void* out_raw)
{
    __shared__ float sTAx[NFORC];
    __shared__ float sTAy[NFORC];

    const int lane = threadIdx.x & 63;
    const int l = lane & 31;                 // layer index
    const bool writer = (lane < NLAYERS);

    // ---- runtime dtype sniff ----
    const __hip_bfloat16* pk_bf = (const __hip_bfloat16*)pk_raw;
    bool in_bf16 = true;
    for (int i = 0; i < 2 * NLAYERS; ++i) {
        float v = __bfloat162float(pk_bf[i]);
        if (!(v > -30.0f && v < -1.0f)) { in_bf16 = false; break; }
    }

    float kin, kout, f;
    if (in_bf16) {
        const __hip_bfloat16* tx = (const __hip_bfloat16*)tax_raw;
        const __hip_bfloat16* ty = (const __hip_bfloat16*)tay_raw;
        const __hip_bfloat16* fcp = (const __hip_bfloat16*)fc_raw;
        kin  = expf(__bfloat162float(pk_bf[2 * l]));
        kout = expf(__bfloat162float(pk_bf[2 * l + 1]));
        f    = __bfloat162float(fcp[0]);
        for (int i = threadIdx.x; i < NFORC; i += 64) {
            sTAx[i] = __bfloat162float(tx[i]);
            sTAy[i] = __bfloat162float(ty[i]);
        }
    } else {
        const float* pk = (const float*)pk_raw;
        const float* tx = (const float*)tax_raw;
        const float* ty = (const float*)tay_raw;
        const float* fcp = (const float*)fc_raw;
        kin  = expf(pk[2 * l]);
        kout = expf(pk[2 * l + 1]);
        f    = fcp[0];
        for (int i = threadIdx.x; i < NFORC; i += 64) {
            sTAx[i] = tx[i];
            sTAy[i] = ty[i];
        }
    }
    __syncthreads();

    __hip_bfloat16* out_bf = (__hip_bfloat16*)out_raw;
    float*          out_f  = (float*)out_raw;
    const int VOFF = NFORC * NLAYERS;        // V block offset in d_out

    // Row 0 of U and V is never set by the scan -> zeros (d_out is poisoned).
    if (writer) {
        if (in_bf16) {
            out_bf[l]        = __float2bfloat16(0.0f);
            out_bf[VOFF + l] = __float2bfloat16(0.0f);
        } else {
            out_f[l]        = 0.0f;
            out_f[VOFF + l] = 0.0f;
        }
    }

    float U = 0.0f, V = 0.0f;
    const bool top    = (lane == 0);         // layer 0: forced by TA, no (U-Uprev) term
    const bool bottom = (l == 31);           // layer 31: Unext = 0

    // iout = 719's result is scattered to row 720 -> dropped by JAX; skip it.
    for (int iout = 0; iout < NFORC - 1; ++iout) {
        const float tax0 = sTAx[iout], tax1 = sTAx[iout + 1];
        const float tay0 = sTAy[iout], tay1 = sTAy[iout + 1];

        #pragma unroll 4
        for (int iin = 0; iin < NSUB; ++iin) {
            const float aa = (float)iin * (1.0f / 60.0f);
            const float taxn = (1.0f - aa) * tax0 + aa * tax1;
            const float tayn = (1.0f - aa) * tay0 + aa * tay1;

            float Um = __shfl_up(U, 1);
            float Vm = __shfl_up(V, 1);
            float Up = __shfl_down(U, 1);
            float Vp = __shfl_down(V, 1);
            if (bottom) { Up = 0.0f; Vp = 0.0f; }

            const float topU = top ? kin * taxn : -kin * (U - Um);
            const float topV = top ? kin * tayn : -kin * (V - Vm);

            const float dU =  f * V + topU - kout * (U - Up);
            const float dV = -f * U + topV - kout * (V - Vp);

            U += DT_STEP * dU;
            V += DT_STEP * dV;
        }

        if (writer) {
            const int row = (iout + 1) * NLAYERS;
            if (in_bf16) {
                out_bf[row + l]        = __float2bfloat16(U);
                out_bf[VOFF + row + l] = __float2bfloat16(V);
            } else {
                out_f[row + l]        = U;
                out_f[VOFF + row + l] = V;
            }
        }
    }
}

extern "C" void kernel_launch(void* const* d_in, const int* in_sizes, int n_in,
                              void* d_out, int out_size, void* d_ws, size_t ws_size,
                              hipStream_t stream) {
    (void)in_sizes; (void)n_in; (void)out_size; (void)d_ws; (void)ws_size;
    junsteak_sim<<<dim3(1), dim3(64), 0, stream>>>(
        d_in[0], d_in[1], d_in[2], d_in[3], d_out);
}

// Round 3
// 256.944 us; speedup vs baseline: 11.6546x; 11.6546x over previous
//
#include <hip/hip_runtime.h>
#include <hip/hip_bf16.h>

#define NLAYERS  32
#define NFORC    720
#define NSUB     60
#define DTS      60.0f

// Linear-system condensation. With W = U + iV the inner step is
//   W <- A W + dt*kin0*((1-aa)cx_s + aa*cx_{s+1}) e0,  A = I + dt(L - i f I)
// so one outer step is W_{s+1} = M W_s + P cx_s + Q cx_{s+1}, M = A^60.
// Phase A (16 waves, 2 columns of I per wave): 60 stencil steps -> M; wave 0
// accumulates P,Q. Phase B (wave 0): 719 sequential complex 32x32 matvecs,
// M rows in registers, x broadcast from LDS, halves combined via shfl_xor(32).
__global__ __launch_bounds__(1024, 1)
void junsteak_cond(const void* pk_raw, const void* tax_raw, const void* tay_raw,
                   const void* fc_raw, void* out_raw)
{
    __shared__ __align__(16) float2 sM[NLAYERS * NLAYERS];  // sM[row*32+col]
    __shared__ __align__(16) float2 sCX[NFORC];             // (TAx, TAy)
    __shared__ __align__(16) float2 sX[NLAYERS];            // current W

    const int t    = threadIdx.x;
    const int lane = t & 63;
    const int wv   = t >> 6;                  // wave 0..15
    const int l    = lane & 31;               // layer / row index
    const int col  = 2 * wv + (lane >> 5);    // matrix column (phase A)

    // ---- runtime dtype sniff (wave-uniform): pk ~ N(-10,0.5) ----
    const __hip_bfloat16* pk_bf = (const __hip_bfloat16*)pk_raw;
    bool in_bf16 = true;
    for (int i = 0; i < 2 * NLAYERS; ++i) {
        float v = __bfloat162float(pk_bf[i]);
        if (!(v > -30.0f && v < -1.0f)) { in_bf16 = false; break; }
    }

    float kin, kout, f, dtkin0;
    if (in_bf16) {
        kin    = expf(__bfloat162float(pk_bf[2 * l]));
        kout   = expf(__bfloat162float(pk_bf[2 * l + 1]));
        f      = __bfloat162float(((const __hip_bfloat16*)fc_raw)[0]);
        dtkin0 = DTS * expf(__bfloat162float(pk_bf[0]));
        const __hip_bfloat16* tx = (const __hip_bfloat16*)tax_raw;
        const __hip_bfloat16* ty = (const __hip_bfloat16*)tay_raw;
        for (int i = t; i < NFORC; i += 1024)
            sCX[i] = make_float2(__bfloat162float(tx[i]), __bfloat162float(ty[i]));
    } else {
        const float* pk = (const float*)pk_raw;
        kin    = expf(pk[2 * l]);
        kout   = expf(pk[2 * l + 1]);
        f      = ((const float*)fc_raw)[0];
        dtkin0 = DTS * expf(pk[0]);
        const float* tx = (const float*)tax_raw;
        const float* ty = (const float*)tay_raw;
        for (int i = t; i < NFORC; i += 1024)
            sCX[i] = make_float2(tx[i], ty[i]);
    }

    __hip_bfloat16* out_bf = (__hip_bfloat16*)out_raw;
    float*          out_f  = (float*)out_raw;
    const int VOFF = NFORC * NLAYERS;

    // Row 0 of U and V: zeros (d_out is poisoned 0xAA).
    if (t < 64) {
        const int off = (t >= 32 ? VOFF : 0) + (t & 31);
        if (in_bf16) out_bf[off] = __float2bfloat16(0.0f); else out_f[off] = 0.0f;
    }

    // ---- Phase A: X = A^60 column-by-column; wave0/col0 accumulates P,Q ----
    float xr = (l == col) ? 1.0f : 0.0f, xi = 0.0f;
    float Pr = 0.f, Pi = 0.f, Qr = 0.f, Qi = 0.f;
    const bool row0  = (l == 0);
    const bool row31 = (l == 31);
    for (int m = 0; m < NSUB; ++m) {
        // P += dtkin0*(m+1)/60 * A^m e0 ; Q += dtkin0*(59-m)/60 * A^m e0
        const float cp = dtkin0 * (float)(m + 1) * (1.0f / 60.0f);
        const float cq = dtkin0 * (float)(NSUB - 1 - m) * (1.0f / 60.0f);
        Pr = fmaf(cp, xr, Pr); Pi = fmaf(cp, xi, Pi);
        Qr = fmaf(cq, xr, Qr); Qi = fmaf(cq, xi, Qi);

        float xrm = __shfl_up(xr, 1);
        float xim = __shfl_up(xi, 1);
        float xrp = __shfl_down(xr, 1);
        float xip = __shfl_down(xi, 1);
        if (row31) { xrp = 0.0f; xip = 0.0f; }   // x_32 = 0 (also blocks col leak)

        const float Lr = row0 ? (-kout * (xr - xrp))
                              : (-kin * (xr - xrm) - kout * (xr - xrp));
        const float Li = row0 ? (-kout * (xi - xip))
                              : (-kin * (xi - xim) - kout * (xi - xip));
        const float nxr = xr + DTS * Lr + DTS * f * xi;
        const float nxi = xi + DTS * Li - DTS * f * xr;
        xr = nxr; xi = nxi;
    }
    sM[l * NLAYERS + col] = make_float2(xr, xi);
    __syncthreads();

    if (t >= 64) return;                     // phase B: wave 0 only

    // ---- Phase B: W_{s+1} = M W_s + P cx_s + Q cx_{s+1}, 719 steps ----
    const int h = lane >> 5;                 // j-half: 0 -> j 0..15, 1 -> 16..31
    const int i = l;                         // row

    float2 Mrow[16];                         // M[i][16h .. 16h+15]
    {
        const float4* rp = (const float4*)(sM + i * NLAYERS + h * 16);
        #pragma unroll
        for (int jj = 0; jj < 8; ++jj) {
            const float4 v = rp[jj];
            Mrow[2 * jj]     = make_float2(v.x, v.y);
            Mrow[2 * jj + 1] = make_float2(v.z, v.w);
        }
    }

    if (h == 0) sX[i] = make_float2(0.0f, 0.0f);   // W_0 = 0 (same-wave DS order)

    const float4* xp = (const float4*)(sX + h * 16);
    float2 cn = sCX[0];

    for (int s = 0; s < NFORC - 1; ++s) {
        const float2 cs = cn;
        cn = sCX[s + 1];

        float a0 = 0.f, a1 = 0.f, a2 = 0.f, a3 = 0.f;
        #pragma unroll
        for (int jj = 0; jj < 8; ++jj) {
            const float4 v = xp[jj];         // x_{2jj}, x_{2jj+1} (broadcast)
            const float2 m0 = Mrow[2 * jj];
            const float2 m1 = Mrow[2 * jj + 1];
            a0 = fmaf(m0.x, v.x, a0); a1 = fmaf(m0.y, v.y, a1);
            a2 = fmaf(m0.x, v.y, a2); a3 = fmaf(m0.y, v.x, a3);
            a0 = fmaf(m1.x, v.z, a0); a1 = fmaf(m1.y, v.w, a1);
            a2 = fmaf(m1.x, v.w, a2); a3 = fmaf(m1.y, v.z, a3);
        }
        float yr = a0 - a1;                  // Re(M x)
        float yi = a2 + a3;                  // Im(M x)
        yr += __shfl_xor(yr, 32);
        yi += __shfl_xor(yi, 32);

        if (h == 0) {
            const float gr = Pr * cs.x - Pi * cs.y + Qr * cn.x - Qi * cn.y;
            const float gi = Pr * cs.y + Pi * cs.x + Qr * cn.y + Qi * cn.x;
            const float wr = yr + gr;
            const float wi = yi + gi;
            sX[i] = make_float2(wr, wi);
            const int row = (s + 1) * NLAYERS + i;
            if (in_bf16) {
                out_bf[row]        = __float2bfloat16(wr);
                out_bf[VOFF + row] = __float2bfloat16(wi);
            } else {
                out_f[row]        = wr;
                out_f[VOFF + row] = wi;
            }
        }
    }
}

extern "C" void kernel_launch(void* const* d_in, const int* in_sizes, int n_in,
                              void* d_out, int out_size, void* d_ws, size_t ws_size,
                              hipStream_t stream) {
    (void)in_sizes; (void)n_in; (void)out_size; (void)d_ws; (void)ws_size;
    junsteak_cond<<<dim3(1), dim3(1024), 0, stream>>>(
        d_in[0], d_in[1], d_in[2], d_in[3], d_out);
}

// Round 4
// 127.787 us; speedup vs baseline: 23.4341x; 2.0107x over previous
//
#include <hip/hip_runtime.h>
#include <hip/hip_bf16.h>

#define NLAYERS 32
#define NFORC   720
#define NSUB    60
#define DTS     60.0f
#define CHUNK   20          // steps per chunk
#define NCHUNK  36          // chunks 0..34 full (20 steps), chunk 35 has 19
// ws layout (float2): zend[NCHUNK][32] @ 0 ; b[NCHUNK][32] @ NCHUNK*32

// ---- shared helpers ----------------------------------------------------
__device__ __forceinline__ bool sniff_bf16(const void* pk_raw) {
    // pk ~ N(-10,0.5): bf16-staged -> all 64 bf16 reads in (-30,-1);
    // f32-staged -> low half-words look random -> rejected a.s.
    const __hip_bfloat16* pk_bf = (const __hip_bfloat16*)pk_raw;
    for (int i = 0; i < 2 * NLAYERS; ++i) {
        float v = __bfloat162float(pk_bf[i]);
        if (!(v > -30.0f && v < -1.0f)) return false;
    }
    return true;
}

__device__ __forceinline__ void load_params(const void* pk_raw, const void* fc_raw,
                                            bool bf, int l, float& kin, float& kout,
                                            float& f, float& dtkin0) {
    if (bf) {
        const __hip_bfloat16* pk = (const __hip_bfloat16*)pk_raw;
        kin    = expf(__bfloat162float(pk[2 * l]));
        kout   = expf(__bfloat162float(pk[2 * l + 1]));
        f      = __bfloat162float(((const __hip_bfloat16*)fc_raw)[0]);
        dtkin0 = DTS * expf(__bfloat162float(pk[0]));
    } else {
        const float* pk = (const float*)pk_raw;
        kin    = expf(pk[2 * l]);
        kout   = expf(pk[2 * l + 1]);
        f      = ((const float*)fc_raw)[0];
        dtkin0 = DTS * expf(pk[0]);
    }
}

// Phase A: column `col` of M = A^60 -> sM; P,Q accumulated (valid on col==0 lanes).
__device__ __forceinline__ void phase_a(float2* sM, int l, int col,
                                        float kin, float kout, float f, float dtkin0,
                                        float& Pr, float& Pi, float& Qr, float& Qi) {
    float xr = (l == col) ? 1.0f : 0.0f, xi = 0.0f;
    Pr = Pi = Qr = Qi = 0.0f;
    const bool row0 = (l == 0), row31 = (l == 31);
    for (int m = 0; m < NSUB; ++m) {
        const float cp = dtkin0 * (float)(m + 1) * (1.0f / 60.0f);
        const float cq = dtkin0 * (float)(NSUB - 1 - m) * (1.0f / 60.0f);
        Pr = fmaf(cp, xr, Pr); Pi = fmaf(cp, xi, Pi);
        Qr = fmaf(cq, xr, Qr); Qi = fmaf(cq, xi, Qi);
        float xrm = __shfl_up(xr, 1);
        float xim = __shfl_up(xi, 1);
        float xrp = __shfl_down(xr, 1);
        float xip = __shfl_down(xi, 1);
        if (row31) { xrp = 0.0f; xip = 0.0f; }   // x_32 = 0 (also blocks col leak)
        const float Lr = row0 ? (-kout * (xr - xrp))
                              : (-kin * (xr - xrm) - kout * (xr - xrp));
        const float Li = row0 ? (-kout * (xi - xip))
                              : (-kin * (xi - xim) - kout * (xi - xip));
        const float nxr = xr + DTS * Lr + DTS * f * xi;
        const float nxi = xi + DTS * Li - DTS * f * xr;
        xr = nxr; xi = nxi;
    }
    sM[l * NLAYERS + col] = make_float2(xr, xi);
}

__device__ __forceinline__ void load_mrow(const float2* sMat, int i, int h, float2* Mrow) {
    const float4* rp = (const float4*)(sMat + i * NLAYERS + h * 16);
    #pragma unroll
    for (int jj = 0; jj < 8; ++jj) {
        const float4 v = rp[jj];
        Mrow[2 * jj]     = make_float2(v.x, v.y);
        Mrow[2 * jj + 1] = make_float2(v.z, v.w);
    }
}

// 64-lane complex matvec: y = Mat * x, x broadcast from sX, halves via shfl_xor(32).
__device__ __forceinline__ void cmatvec(const float2* Mrow, const float2* sX, int h,
                                        float& yr, float& yi) {
    const float4* xp = (const float4*)(sX + h * 16);
    float a0 = 0.f, a1 = 0.f, a2 = 0.f, a3 = 0.f;
    #pragma unroll
    for (int jj = 0; jj < 8; ++jj) {
        const float4 v = xp[jj];
        const float2 m0 = Mrow[2 * jj];
        const float2 m1 = Mrow[2 * jj + 1];
        a0 = fmaf(m0.x, v.x, a0); a1 = fmaf(m0.y, v.y, a1);
        a2 = fmaf(m0.x, v.y, a2); a3 = fmaf(m0.y, v.x, a3);
        a0 = fmaf(m1.x, v.z, a0); a1 = fmaf(m1.y, v.w, a1);
        a2 = fmaf(m1.x, v.w, a2); a3 = fmaf(m1.y, v.z, a3);
    }
    yr = a0 - a1; yi = a2 + a3;
    yr += __shfl_xor(yr, 32);
    yi += __shfl_xor(yi, 32);
}

// 32x32 complex matmul in LDS, 1024 threads, thread t -> entry (t>>5, t&31).
__device__ __forceinline__ void cmatmul(float2* D, const float2* A, const float2* B, int t) {
    const int i = t >> 5, j = t & 31;
    float ar = 0.f, ai = 0.f;
    #pragma unroll 8
    for (int k = 0; k < 32; ++k) {
        const float2 a = A[i * 32 + k];
        const float2 b = B[k * 32 + j];
        ar = fmaf(a.x, b.x, fmaf(-a.y, b.y, ar));
        ai = fmaf(a.x, b.y, fmaf( a.y, b.x, ai));
    }
    D[i * 32 + j] = make_float2(ar, ai);
}

// ---- K1: per-chunk particular solution from zero state -> zend[c] ------
__global__ __launch_bounds__(1024, 1)
void k1_pass1(const void* pk_raw, const void* tax_raw, const void* tay_raw,
              const void* fc_raw, float2* ws)
{
    __shared__ __align__(16) float2 sM[NLAYERS * NLAYERS];
    __shared__ __align__(16) float2 sCX[NFORC];
    __shared__ __align__(16) float2 sX[NLAYERS];

    const int t = threadIdx.x, lane = t & 63, wv = t >> 6;
    const int l = lane & 31, col = 2 * wv + (lane >> 5);
    const int c = blockIdx.x;

    const bool bf = sniff_bf16(pk_raw);
    float kin, kout, f, dtkin0;
    load_params(pk_raw, fc_raw, bf, l, kin, kout, f, dtkin0);
    if (bf) {
        const __hip_bfloat16* tx = (const __hip_bfloat16*)tax_raw;
        const __hip_bfloat16* ty = (const __hip_bfloat16*)tay_raw;
        for (int i = t; i < NFORC; i += 1024)
            sCX[i] = make_float2(__bfloat162float(tx[i]), __bfloat162float(ty[i]));
    } else {
        const float* tx = (const float*)tax_raw;
        const float* ty = (const float*)tay_raw;
        for (int i = t; i < NFORC; i += 1024)
            sCX[i] = make_float2(tx[i], ty[i]);
    }

    float Pr, Pi, Qr, Qi;
    phase_a(sM, l, col, kin, kout, f, dtkin0, Pr, Pi, Qr, Qi);
    __syncthreads();
    if (t >= 64) return;

    const int h = lane >> 5, i = l;
    float2 Mrow[16];
    load_mrow(sM, i, h, Mrow);
    if (h == 0) sX[i] = make_float2(0.0f, 0.0f);   // same-wave DS order

    const int a = c * CHUNK;
    const int b = min(a + CHUNK, NFORC - 1);
    float2 wlast = make_float2(0.0f, 0.0f);
    float2 cn = sCX[a];
    for (int s = a; s < b; ++s) {
        const float2 cs = cn;
        cn = sCX[s + 1];
        float yr, yi;
        cmatvec(Mrow, sX, h, yr, yi);
        if (h == 0) {
            const float gr = Pr * cs.x - Pi * cs.y + Qr * cn.x - Qi * cn.y;
            const float gi = Pr * cs.y + Pi * cs.x + Qr * cn.y + Qi * cn.x;
            wlast = make_float2(yr + gr, yi + gi);
            sX[i] = wlast;
        }
    }
    if (h == 0) ws[c * 32 + i] = wlast;            // zend[c]
}

// ---- K2: E = M^20 by squaring; sequential coarse chain b_{c+1}=E b_c + z_c
__global__ __launch_bounds__(1024, 1)
void k2_combine(const void* pk_raw, const void* fc_raw, float2* ws)
{
    __shared__ __align__(16) float2 sM[1024];
    __shared__ __align__(16) float2 sU[1024];
    __shared__ __align__(16) float2 sV[1024];
    __shared__ __align__(16) float2 sT[1024];
    __shared__ __align__(16) float2 sZ[NCHUNK * 32];
    __shared__ __align__(16) float2 sX[NLAYERS];

    const int t = threadIdx.x, lane = t & 63, wv = t >> 6;
    const int l = lane & 31, col = 2 * wv + (lane >> 5);

    const bool bf = sniff_bf16(pk_raw);
    float kin, kout, f, dtkin0;
    load_params(pk_raw, fc_raw, bf, l, kin, kout, f, dtkin0);

    for (int idx = t; idx < NCHUNK * 32; idx += 1024) sZ[idx] = ws[idx];  // zend

    float Pr, Pi, Qr, Qi;
    phase_a(sM, l, col, kin, kout, f, dtkin0, Pr, Pi, Qr, Qi);
    __syncthreads();

    cmatmul(sU, sM, sM, t); __syncthreads();   // M^2
    cmatmul(sV, sU, sU, t); __syncthreads();   // M^4
    cmatmul(sT, sV, sV, t); __syncthreads();   // M^8
    cmatmul(sU, sT, sT, t); __syncthreads();   // M^16
    cmatmul(sT, sU, sV, t); __syncthreads();   // E = M^16 * M^4 = M^20
    if (t >= 64) return;

    const int h = lane >> 5, i = l;
    float2 Erow[16];
    load_mrow(sT, i, h, Erow);
    if (h == 0) sX[i] = make_float2(0.0f, 0.0f);

    float2* bws = ws + NCHUNK * 32;
    float2 breg = make_float2(0.0f, 0.0f);
    for (int c = 0; c < NCHUNK; ++c) {
        if (h == 0) bws[c * 32 + i] = breg;        // b_c
        if (c == NCHUNK - 1) break;
        float yr, yi;
        cmatvec(Erow, sX, h, yr, yi);
        if (h == 0) {
            const float2 z = sZ[c * 32 + i];
            breg = make_float2(yr + z.x, yi + z.y);
            sX[i] = breg;
        }
    }
}

// ---- K3: re-integrate each chunk from true initial state, write outputs -
__global__ __launch_bounds__(1024, 1)
void k3_pass2(const void* pk_raw, const void* tax_raw, const void* tay_raw,
              const void* fc_raw, const float2* ws, void* out_raw)
{
    __shared__ __align__(16) float2 sM[NLAYERS * NLAYERS];
    __shared__ __align__(16) float2 sCX[NFORC];
    __shared__ __align__(16) float2 sX[NLAYERS];

    const int t = threadIdx.x, lane = t & 63, wv = t >> 6;
    const int l = lane & 31, col = 2 * wv + (lane >> 5);
    const int c = blockIdx.x;

    const bool bf = sniff_bf16(pk_raw);
    float kin, kout, f, dtkin0;
    load_params(pk_raw, fc_raw, bf, l, kin, kout, f, dtkin0);
    if (bf) {
        const __hip_bfloat16* tx = (const __hip_bfloat16*)tax_raw;
        const __hip_bfloat16* ty = (const __hip_bfloat16*)tay_raw;
        for (int i = t; i < NFORC; i += 1024)
            sCX[i] = make_float2(__bfloat162float(tx[i]), __bfloat162float(ty[i]));
    } else {
        const float* tx = (const float*)tax_raw;
        const float* ty = (const float*)tay_raw;
        for (int i = t; i < NFORC; i += 1024)
            sCX[i] = make_float2(tx[i], ty[i]);
    }

    __hip_bfloat16* out_bf = (__hip_bfloat16*)out_raw;
    float*          out_f  = (float*)out_raw;
    const int VOFF = NFORC * NLAYERS;

    // Row 0 zeros (d_out poisoned): block 0 only.
    if (c == 0 && t < 64) {
        const int off = (t >= 32 ? VOFF : 0) + (t & 31);
        if (bf) out_bf[off] = __float2bfloat16(0.0f); else out_f[off] = 0.0f;
    }

    float Pr, Pi, Qr, Qi;
    phase_a(sM, l, col, kin, kout, f, dtkin0, Pr, Pi, Qr, Qi);
    __syncthreads();
    if (t >= 64) return;

    const int h = lane >> 5, i = l;
    float2 Mrow[16];
    load_mrow(sM, i, h, Mrow);
    const float2* bws = ws + NCHUNK * 32;
    if (h == 0) sX[i] = bws[c * 32 + i];           // true initial state b_c

    const int a = c * CHUNK;
    const int b = min(a + CHUNK, NFORC - 1);
    float2 cn = sCX[a];
    for (int s = a; s < b; ++s) {
        const float2 cs = cn;
        cn = sCX[s + 1];
        float yr, yi;
        cmatvec(Mrow, sX, h, yr, yi);
        if (h == 0) {
            const float gr = Pr * cs.x - Pi * cs.y + Qr * cn.x - Qi * cn.y;
            const float gi = Pr * cs.y + Pi * cs.x + Qr * cn.y + Qi * cn.x;
            const float wr = yr + gr, wi = yi + gi;
            sX[i] = make_float2(wr, wi);
            const int row = (s + 1) * NLAYERS + i;
            if (bf) {
                out_bf[row]        = __float2bfloat16(wr);
                out_bf[VOFF + row] = __float2bfloat16(wi);
            } else {
                out_f[row]        = wr;
                out_f[VOFF + row] = wi;
            }
        }
    }
}

extern "C" void kernel_launch(void* const* d_in, const int* in_sizes, int n_in,
                              void* d_out, int out_size, void* d_ws, size_t ws_size,
                              hipStream_t stream) {
    (void)in_sizes; (void)n_in; (void)out_size; (void)ws_size;
    float2* ws = (float2*)d_ws;
    k1_pass1 <<<dim3(NCHUNK), dim3(1024), 0, stream>>>(d_in[0], d_in[1], d_in[2], d_in[3], ws);
    k2_combine<<<dim3(1),      dim3(1024), 0, stream>>>(d_in[0], d_in[3], ws);
    k3_pass2 <<<dim3(NCHUNK), dim3(1024), 0, stream>>>(d_in[0], d_in[1], d_in[2], d_in[3], ws, d_out);
}